// Round 4
// baseline (344.197 us; speedup 1.0000x reference)
//
#include <hip/hip_runtime.h>

// out[b,o,n] = sum_{i,k} x[b,i,4n+k] * w[o,i,4n+k] / sqrt(128)
// x: (64,128,4096) f32, w: (128,128,4096) f32, out: (64,128,1024) f32.
//
// Round-4: ZERO LDS, ZERO barriers. Rounds 1-3 were phase-serialized
// (1 block/CU, barrier drains). Here each wave independently computes a
// 32b x 32o x 4n tile with 2x2 of mfma_f32_16x16x32_bf16, loading MFMA
// fragments DIRECTLY from global memory (fragment = 8 contiguous k =
// 2 cin x 4 blk = two float4 loads, 16KB apart) and converting fp32->bf16
// in-register. Reuse via L1 (4 oq-waves per block load identical x) and
// L2 (block cluster {ng-pair x bq-pair} on one XCD shares every 128B line).
// 32 independent loads per kk-step overlap their latencies; no sync at all.

#define CIN  128
#define COUT 128
#define ODIM 1024
#define DDIM 4096

typedef short bf16x8 __attribute__((ext_vector_type(8)));
typedef float f32x4  __attribute__((ext_vector_type(4)));

static __device__ __forceinline__ unsigned short f2bf(float f) {
    unsigned int u = __float_as_uint(f);
    u += 0x7fffu + ((u >> 16) & 1u);   // RNE fp32 -> bf16
    return (unsigned short)(u >> 16);
}
static __device__ __forceinline__ bf16x8 mkfrag(float4 a, float4 b) {
    bf16x8 r;
    r[0] = (short)f2bf(a.x); r[1] = (short)f2bf(a.y);
    r[2] = (short)f2bf(a.z); r[3] = (short)f2bf(a.w);
    r[4] = (short)f2bf(b.x); r[5] = (short)f2bf(b.y);
    r[6] = (short)f2bf(b.z); r[7] = (short)f2bf(b.w);
    return r;
}

__global__ __launch_bounds__(256, 2)
void nolc_kernel(const float* __restrict__ xg,
                 const float* __restrict__ wg,
                 float* __restrict__ outg) {
    const int bid  = blockIdx.x;
    // XCD-contiguous gidx; cluster of 4 consecutive gidx = {ng-pair x bq-pair}
    const int gidx = (bid & 7) * 64 + (bid >> 3);     // 512 blocks
    const int bq   = (gidx >> 1) & 1;                  // b-half
    const int ng   = (gidx >> 2) * 2 + (gidx & 1);     // 0..255 (4 n each)

    const int lane = threadIdx.x & 63;
    const int oq   = threadIdx.x >> 6;                 // wave 0..3 -> o-quarter
    const int row  = lane & 15;
    const int kg   = lane >> 4;                        // 0..3

    const int d0 = ng * 16;                            // float offset in D

    // A rows: b = bq*32 + bh*16 + row ; i = kk*8 + kg*2 + j
    const float* xr0 = xg + ((size_t)(bq * 32 + row) * CIN + kg * 2) * DDIM + d0;
    const float* xr1 = xr0 + (size_t)16 * CIN * DDIM;
    // B cols: o = oq*32 + oh*16 + row
    const float* wr0 = wg + ((size_t)(oq * 32 + row) * CIN + kg * 2) * DDIM + d0;
    const float* wr1 = wr0 + (size_t)16 * CIN * DDIM;

    f32x4 acc[2][2][4];   // [bh][oh][nn]
#pragma unroll
    for (int bh = 0; bh < 2; ++bh)
#pragma unroll
        for (int oh = 0; oh < 2; ++oh)
#pragma unroll
            for (int nn = 0; nn < 4; ++nn)
                acc[bh][oh][nn] = (f32x4){0.f, 0.f, 0.f, 0.f};

#pragma unroll 1
    for (int kk = 0; kk < 16; ++kk) {
        const size_t ko = (size_t)kk * 8 * DDIM;

        // ---- burst-issue all 32 independent loads (latencies overlap) ----
        float4 fa[2][4][2], fb[2][4][2];   // [half][nn][j], static-indexed only
#pragma unroll
        for (int nn = 0; nn < 4; ++nn)
#pragma unroll
            for (int j = 0; j < 2; ++j) {
                fa[0][nn][j] = *reinterpret_cast<const float4*>(xr0 + ko + j * DDIM + nn * 4);
                fa[1][nn][j] = *reinterpret_cast<const float4*>(xr1 + ko + j * DDIM + nn * 4);
            }
#pragma unroll
        for (int nn = 0; nn < 4; ++nn)
#pragma unroll
            for (int j = 0; j < 2; ++j) {
                fb[0][nn][j] = *reinterpret_cast<const float4*>(wr0 + ko + j * DDIM + nn * 4);
                fb[1][nn][j] = *reinterpret_cast<const float4*>(wr1 + ko + j * DDIM + nn * 4);
            }

        // ---- convert (frees fa, then fb) ----
        bf16x8 A[2][4], B[2][4];
#pragma unroll
        for (int bh = 0; bh < 2; ++bh)
#pragma unroll
            for (int nn = 0; nn < 4; ++nn)
                A[bh][nn] = mkfrag(fa[bh][nn][0], fa[bh][nn][1]);
#pragma unroll
        for (int oh = 0; oh < 2; ++oh)
#pragma unroll
            for (int nn = 0; nn < 4; ++nn)
                B[oh][nn] = mkfrag(fb[oh][nn][0], fb[oh][nn][1]);

        // ---- 16 MFMA ----
#pragma unroll
        for (int nn = 0; nn < 4; ++nn)
#pragma unroll
            for (int bh = 0; bh < 2; ++bh)
#pragma unroll
                for (int oh = 0; oh < 2; ++oh)
                    acc[bh][oh][nn] = __builtin_amdgcn_mfma_f32_16x16x32_bf16(
                        A[bh][nn], B[oh][nn], acc[bh][oh][nn], 0, 0, 0);
    }

    // ---- epilogue: C/D layout col=lane&15 (=o), row=kg*4+reg (=b) ----
    const float scale = 0.08838834764831845f;  // 1/sqrt(128)
#pragma unroll
    for (int bh = 0; bh < 2; ++bh)
#pragma unroll
        for (int oh = 0; oh < 2; ++oh) {
            const int o = oq * 32 + oh * 16 + row;
#pragma unroll
            for (int r = 0; r < 4; ++r) {
                const int b = bq * 32 + bh * 16 + kg * 4 + r;
                float4 v;
                v.x = acc[bh][oh][0][r] * scale;
                v.y = acc[bh][oh][1][r] * scale;
                v.z = acc[bh][oh][2][r] * scale;
                v.w = acc[bh][oh][3][r] * scale;
                *reinterpret_cast<float4*>(outg + ((size_t)b * COUT + o) * ODIM + ng * 4) = v;
            }
        }
}

extern "C" void kernel_launch(void* const* d_in, const int* in_sizes, int n_in,
                              void* d_out, int out_size, void* d_ws, size_t ws_size,
                              hipStream_t stream) {
    const float* x = (const float*)d_in[0];
    const float* w = (const float*)d_in[1];
    float* out = (float*)d_out;
    nolc_kernel<<<dim3(512), dim3(256), 0, stream>>>(x, w, out);
}

// Round 5
// 140.466 us; speedup vs baseline: 2.4504x; 2.4504x over previous
//
#include <hip/hip_runtime.h>

// out[b,o,n] = sum_{i,k} x[b,i,4n+k] * w[o,i,4n+k] / sqrt(128)
// x: (64,128,4096) f32, w: (128,128,4096) f32, out: (64,128,1024) f32.
//
// Round-5: 256B DRAM runs + 2 blocks/CU.
// Block = 32b x 32o x 16n. Grid 512 = 64 ng x 2 bq x 4 oq, the 8 sibling
// blocks of one ng packed on one XCD (x-dup x4 / w-dup x2 dedup in L2;
// HBM-unique stays 384 MB). Single 64 KB LDS buffer (2 blocks/CU resident),
// 2-barrier phase per i-chunk (CI=8, K=32); the co-resident sibling block
// fills all stall time. Depth-1 register prefetch of the x-half keeps 8
// global loads in flight across both barriers.
// LDS layout [row][i][n ^ (row&15)] -> 4-way-over-all-banks on write and
// read (the b64 floor), i.e. conflict-free.

#define CIN  128
#define COUT 128
#define ODIM 1024
#define DDIM 4096
#define NB   16            // n per block (256B d-span)
#define CI   8             // i per chunk -> K = 32
#define NCH  16
#define RS   512           // shorts per LDS row: 8i * 16n * 4k

typedef short bf16x8 __attribute__((ext_vector_type(8)));
typedef short s16x4  __attribute__((ext_vector_type(4)));
typedef float f32x4  __attribute__((ext_vector_type(4)));

static __device__ __forceinline__ unsigned short f2bf(float f) {
    unsigned int u = __float_as_uint(f);
    u += 0x7fffu + ((u >> 16) & 1u);   // RNE fp32 -> bf16
    return (unsigned short)(u >> 16);
}
static __device__ __forceinline__ s16x4 cvt4(float4 v) {
    s16x4 s;
    s[0] = (short)f2bf(v.x); s[1] = (short)f2bf(v.y);
    s[2] = (short)f2bf(v.z); s[3] = (short)f2bf(v.w);
    return s;
}

__global__ __launch_bounds__(512, 4)
void nolc_kernel(const float* __restrict__ xg,
                 const float* __restrict__ wg,
                 float* __restrict__ outg) {
    __shared__ short lds[64 * RS];   // 64 KB: rows 0-31 = x (b), 32-63 = w (o)

    const int bid  = blockIdx.x;
    const int gidx = (bid & 7) * 64 + (bid >> 3);   // XCD-contiguous
    const int ng   = gidx >> 3;                      // 0..63 (16 n each)
    const int bq   = (gidx >> 2) & 1;                // b-half
    const int oq   = gidx & 3;                       // o-quarter

    const int t    = threadIdx.x;
    const int lane = t & 63;
    const int wave = t >> 6;                         // 0..7

    // ---- staging decomposition: unit = (row, i, n) 16B fp32 ----
    const int sn = t & 15;          // n
    const int si = (t >> 4) & 7;    // i within chunk
    const int rl = t >> 7;          // 0..3 (row low bits; it*4 + rl)
    const size_t R4 = (size_t)4 * CIN * DDIM;        // +4 rows
    const size_t CH = (size_t)CI * DDIM;             // +8 i (next chunk)

    const float* px = xg + ((size_t)(bq * 32 + rl) * CIN + si) * DDIM + ng * 64 + sn * 4;
    const float* pw = wg + ((size_t)(oq * 32 + rl) * CIN + si) * DDIM + ng * 64 + sn * 4;

    // ---- compute decomposition: 8 waves = 2bt x 2ot x 2nh ----
    const int bt  = wave & 1;
    const int ot  = (wave >> 1) & 1;
    const int nh  = wave >> 2;       // n-half (8 n each)
    const int r16 = lane & 15;
    const int kg  = lane >> 4;

    f32x4 acc[8];
#pragma unroll
    for (int n = 0; n < 8; ++n) acc[n] = (f32x4){0.f, 0.f, 0.f, 0.f};

    float4 rx[8], rw[8];

#define LOADX(c)                                                              \
    do {                                                                      \
        const float* _p = px + (size_t)(c) * CH;                              \
        _Pragma("unroll")                                                     \
        for (int it = 0; it < 8; ++it)                                        \
            rx[it] = *reinterpret_cast<const float4*>(_p + it * R4);          \
    } while (0)

#define LOADW(c)                                                              \
    do {                                                                      \
        const float* _p = pw + (size_t)(c) * CH;                              \
        _Pragma("unroll")                                                     \
        for (int it = 0; it < 8; ++it)                                        \
            rw[it] = *reinterpret_cast<const float4*>(_p + it * R4);          \
    } while (0)

    // LDS addr (shorts): row*RS + i*64 + ((n ^ (row&15))<<2)
#define STAGEX()                                                              \
    do {                                                                      \
        _Pragma("unroll")                                                     \
        for (int it = 0; it < 8; ++it) {                                      \
            const int row = it * 4 + rl;                                      \
            *reinterpret_cast<s16x4*>(                                        \
                &lds[row * RS + si * 64 + ((sn ^ (row & 15)) << 2)]) = cvt4(rx[it]); \
        }                                                                     \
    } while (0)

#define STAGEW()                                                              \
    do {                                                                      \
        _Pragma("unroll")                                                     \
        for (int it = 0; it < 8; ++it) {                                      \
            const int row = 32 + it * 4 + rl;                                 \
            *reinterpret_cast<s16x4*>(                                        \
                &lds[row * RS + si * 64 + ((sn ^ (row & 15)) << 2)]) = cvt4(rw[it]); \
        }                                                                     \
    } while (0)

    const int xbase = (bt * 16 + r16) * RS;        // x LDS row base
    const int wbase = (32 + ot * 16 + r16) * RS;   // w LDS row base

    LOADX(0);
#pragma unroll 1
    for (int c = 0; c < NCH; ++c) {
        LOADW(c);                       // 8 w-loads in flight
        STAGEX();                       // consumes rx (chunk c)
        if (c + 1 < NCH) LOADX(c + 1);  // prefetch: in flight across barriers
        STAGEW();                       // waits w arrival (counted vmcnt)
        asm volatile("s_waitcnt lgkmcnt(0)" ::: "memory");
        __builtin_amdgcn_s_barrier();

        // ---- compute: per wave 8 MFMA (K=32), frag = 2 x ds_read_b64 ----
#pragma unroll
        for (int nn = 0; nn < 8; ++nn) {
            const int n  = nh * 8 + nn;
            const int so = (n ^ r16) << 2;
            s16x4 a0 = *reinterpret_cast<const s16x4*>(&lds[xbase + (kg * 2) * 64 + so]);
            s16x4 a1 = *reinterpret_cast<const s16x4*>(&lds[xbase + (kg * 2 + 1) * 64 + so]);
            s16x4 b0 = *reinterpret_cast<const s16x4*>(&lds[wbase + (kg * 2) * 64 + so]);
            s16x4 b1 = *reinterpret_cast<const s16x4*>(&lds[wbase + (kg * 2 + 1) * 64 + so]);
            bf16x8 A = __builtin_shufflevector(a0, a1, 0, 1, 2, 3, 4, 5, 6, 7);
            bf16x8 B = __builtin_shufflevector(b0, b1, 0, 1, 2, 3, 4, 5, 6, 7);
            acc[nn] = __builtin_amdgcn_mfma_f32_16x16x32_bf16(A, B, acc[nn], 0, 0, 0);
        }
        if (c + 1 < NCH) __builtin_amdgcn_s_barrier();  // LDS reuse guard
    }

    // ---- epilogue: col = o-local (lane&15), row = b-local (kg*4+reg) ----
    const float scale = 0.08838834764831845f;  // 1/sqrt(128)
    const int o = oq * 32 + ot * 16 + r16;
#pragma unroll
    for (int r = 0; r < 4; ++r) {
        const int b = bq * 32 + bt * 16 + kg * 4 + r;
        float* op = outg + ((size_t)b * COUT + o) * ODIM + ng * 16 + nh * 8;
        float4 v0, v1;
        v0.x = acc[0][r] * scale; v0.y = acc[1][r] * scale;
        v0.z = acc[2][r] * scale; v0.w = acc[3][r] * scale;
        v1.x = acc[4][r] * scale; v1.y = acc[5][r] * scale;
        v1.z = acc[6][r] * scale; v1.w = acc[7][r] * scale;
        *reinterpret_cast<float4*>(op)     = v0;
        *reinterpret_cast<float4*>(op + 4) = v1;
    }
#undef LOADX
#undef LOADW
#undef STAGEX
#undef STAGEW
}

extern "C" void kernel_launch(void* const* d_in, const int* in_sizes, int n_in,
                              void* d_out, int out_size, void* d_ws, size_t ws_size,
                              hipStream_t stream) {
    const float* x = (const float*)d_in[0];
    const float* w = (const float*)d_in[1];
    float* out = (float*)d_out;
    nolc_kernel<<<dim3(512), dim3(512), 0, stream>>>(x, w, out);
}

// Round 6
// 140.189 us; speedup vs baseline: 2.4552x; 1.0020x over previous
//
#include <hip/hip_runtime.h>

// out[b,o,n] = sum_{i,k} x[b,i,4n+k] * w[o,i,4n+k] / sqrt(128)
// x: (64,128,4096) f32, w: (128,128,4096) f32, out: (64,128,1024) f32.
//
// Round-6: r5 geometry unchanged (32b x 32o x 16n, 256B runs, 64 KB LDS,
// XOR swizzle conflict-free, 2 blocks/CU). ONLY change: staging loads are
// inline-asm global_load_dwordx4 (sgpr base + u32 voffset) whose results
// are register-pinned -> compiler CANNOT recycle/serialize them (r2/r3/r5
// all showed VGPR=64: the "prefetch" was silently serialized, exposing
// full load latency every chunk -> invariant ~165us). Depth-1-chunk
// pipeline with counted vmcnt(8), sched_barrier(0) fences after waits.

#define CIN  128
#define COUT 128
#define ODIM 1024
#define DDIM 4096
#define CI   8
#define NCH  16
#define RS   512                         // shorts per LDS row
#define R4B  (4u * CIN * DDIM * 4u)      // +4 rows, bytes (8 MiB)
#define CHB  ((unsigned)(CI * DDIM * 4)) // +1 i-chunk, bytes (128 KiB)

typedef short bf16x8 __attribute__((ext_vector_type(8)));
typedef short s16x4  __attribute__((ext_vector_type(4)));
typedef float f32x4  __attribute__((ext_vector_type(4)));

static __device__ __forceinline__ unsigned short f2bf(float f) {
    unsigned int u = __float_as_uint(f);
    u += 0x7fffu + ((u >> 16) & 1u);   // RNE fp32 -> bf16
    return (unsigned short)(u >> 16);
}
static __device__ __forceinline__ s16x4 cvt4(float4 v) {
    s16x4 s;
    s[0] = (short)f2bf(v.x); s[1] = (short)f2bf(v.y);
    s[2] = (short)f2bf(v.z); s[3] = (short)f2bf(v.w);
    return s;
}

__global__ __launch_bounds__(512, 4)
void nolc_kernel(const float* __restrict__ xg,
                 const float* __restrict__ wg,
                 float* __restrict__ outg) {
    __shared__ short lds[64 * RS];   // 64 KB: rows 0-31 x(b), 32-63 w(o)

    const int bid  = blockIdx.x;
    const int gidx = (bid & 7) * 64 + (bid >> 3);   // XCD-contiguous
    const int ng   = gidx >> 3;                      // 0..63 (16 n each)
    const int bq   = (gidx >> 2) & 1;
    const int oq   = gidx & 3;

    const int t    = threadIdx.x;
    const int lane = t & 63;
    const int wave = t >> 6;

    // staging decomposition (16B unit): sn(n) x si(i) x rl(row low)
    const int sn = t & 15;
    const int si = (t >> 4) & 7;
    const int rl = t >> 7;          // 0..3

    const unsigned xoff =
        ((unsigned)((bq * 32 + rl) * CIN + si) * DDIM + (unsigned)(ng * 64 + sn * 4)) * 4u;
    const unsigned woff =
        ((unsigned)((oq * 32 + rl) * CIN + si) * DDIM + (unsigned)(ng * 64 + sn * 4)) * 4u;

    // compute decomposition: 8 waves = 2bt x 2ot x 2nh
    const int bt  = wave & 1;
    const int ot  = (wave >> 1) & 1;
    const int nh  = wave >> 2;
    const int r16 = lane & 15;
    const int kg  = lane >> 4;

    f32x4 acc[8];
#pragma unroll
    for (int n = 0; n < 8; ++n) acc[n] = (f32x4){0.f, 0.f, 0.f, 0.f};

    float4 fx0, fx1, fx2, fx3, fx4, fx5, fx6, fx7;
    float4 fw0, fw1, fw2, fw3, fw4, fw5, fw6, fw7;

#define GLD(dst, off, base) \
    asm volatile("global_load_dwordx4 %0, %1, %2" : "=v"(dst) : "v"(off), "s"(base))

#define ISSUE_X(c) do { unsigned _o = xoff + (unsigned)(c) * CHB;            \
    GLD(fx0, _o,           xg); GLD(fx1, _o + 1u*R4B, xg);                   \
    GLD(fx2, _o + 2u*R4B,  xg); GLD(fx3, _o + 3u*R4B, xg);                   \
    GLD(fx4, _o + 4u*R4B,  xg); GLD(fx5, _o + 5u*R4B, xg);                   \
    GLD(fx6, _o + 6u*R4B,  xg); GLD(fx7, _o + 7u*R4B, xg); } while (0)

#define ISSUE_W(c) do { unsigned _o = woff + (unsigned)(c) * CHB;            \
    GLD(fw0, _o,           wg); GLD(fw1, _o + 1u*R4B, wg);                   \
    GLD(fw2, _o + 2u*R4B,  wg); GLD(fw3, _o + 3u*R4B, wg);                   \
    GLD(fw4, _o + 4u*R4B,  wg); GLD(fw5, _o + 5u*R4B, wg);                   \
    GLD(fw6, _o + 6u*R4B,  wg); GLD(fw7, _o + 7u*R4B, wg); } while (0)

    // LDS addr (shorts): row*RS + si*64 + ((sn ^ (row&15))<<2)
#define STROW(v, it, rbase) do {                                             \
    const int _row = (rbase) + (it) * 4 + rl;                                \
    *reinterpret_cast<s16x4*>(                                               \
        &lds[_row * RS + si * 64 + ((sn ^ (_row & 15)) << 2)]) = cvt4(v);    \
    } while (0)

#define STX() do { STROW(fx0,0,0); STROW(fx1,1,0); STROW(fx2,2,0); STROW(fx3,3,0); \
                   STROW(fx4,4,0); STROW(fx5,5,0); STROW(fx6,6,0); STROW(fx7,7,0); } while (0)
#define STW() do { STROW(fw0,0,32); STROW(fw1,1,32); STROW(fw2,2,32); STROW(fw3,3,32); \
                   STROW(fw4,4,32); STROW(fw5,5,32); STROW(fw6,6,32); STROW(fw7,7,32); } while (0)

#define VMW8() do { asm volatile("s_waitcnt vmcnt(8)" ::: "memory");         \
                    __builtin_amdgcn_sched_barrier(0); } while (0)
#define VMW0() do { asm volatile("s_waitcnt vmcnt(0)" ::: "memory");         \
                    __builtin_amdgcn_sched_barrier(0); } while (0)

    const int xbase = (bt * 16 + r16) * RS;
    const int wbase = (32 + ot * 16 + r16) * RS;

    ISSUE_X(0);
    ISSUE_W(0);

#pragma unroll 1
    for (int c = 0; c < NCH; ++c) {
        VMW8();                          // x(c) done (w(c) still outstanding)
        STX();
        if (c + 1 < NCH) ISSUE_X(c + 1); // outstanding: w(c) 8 + x(c+1) 8

        if (c + 1 < NCH) { VMW8(); }     // w(c) done, x(c+1) in flight
        else             { VMW0(); }
        STW();
        if (c + 1 < NCH) ISSUE_W(c + 1);

        asm volatile("s_waitcnt lgkmcnt(0)" ::: "memory");
        __builtin_amdgcn_sched_barrier(0);
        __builtin_amdgcn_s_barrier();

#pragma unroll
        for (int nn = 0; nn < 8; ++nn) {
            const int n  = nh * 8 + nn;
            const int so = (n ^ r16) << 2;
            s16x4 a0 = *reinterpret_cast<const s16x4*>(&lds[xbase + (kg * 2) * 64 + so]);
            s16x4 a1 = *reinterpret_cast<const s16x4*>(&lds[xbase + (kg * 2 + 1) * 64 + so]);
            s16x4 b0 = *reinterpret_cast<const s16x4*>(&lds[wbase + (kg * 2) * 64 + so]);
            s16x4 b1 = *reinterpret_cast<const s16x4*>(&lds[wbase + (kg * 2 + 1) * 64 + so]);
            bf16x8 A = __builtin_shufflevector(a0, a1, 0, 1, 2, 3, 4, 5, 6, 7);
            bf16x8 B = __builtin_shufflevector(b0, b1, 0, 1, 2, 3, 4, 5, 6, 7);
            acc[nn] = __builtin_amdgcn_mfma_f32_16x16x32_bf16(A, B, acc[nn], 0, 0, 0);
        }
        if (c + 1 < NCH) __builtin_amdgcn_s_barrier();   // LDS reuse guard
    }

    // epilogue: col = o-local (lane&15), row = b-local (kg*4+reg)
    const float scale = 0.08838834764831845f;  // 1/sqrt(128)
    const int o = oq * 32 + ot * 16 + r16;
#pragma unroll
    for (int r = 0; r < 4; ++r) {
        const int b = bq * 32 + bt * 16 + kg * 4 + r;
        float* op = outg + ((size_t)b * COUT + o) * ODIM + ng * 16 + nh * 8;
        float4 v0, v1;
        v0.x = acc[0][r] * scale; v0.y = acc[1][r] * scale;
        v0.z = acc[2][r] * scale; v0.w = acc[3][r] * scale;
        v1.x = acc[4][r] * scale; v1.y = acc[5][r] * scale;
        v1.z = acc[6][r] * scale; v1.w = acc[7][r] * scale;
        *reinterpret_cast<float4*>(op)     = v0;
        *reinterpret_cast<float4*>(op + 4) = v1;
    }
}

extern "C" void kernel_launch(void* const* d_in, const int* in_sizes, int n_in,
                              void* d_out, int out_size, void* d_ws, size_t ws_size,
                              hipStream_t stream) {
    const float* x = (const float*)d_in[0];
    const float* w = (const float*)d_in[1];
    float* out = (float*)d_out;
    nolc_kernel<<<dim3(512), dim3(512), 0, stream>>>(x, w, out);
}